// Round 21
// baseline (108.360 us; speedup 1.0000x reference)
//
#include <hip/hip_runtime.h>
#include <cstdint>

typedef __attribute__((ext_vector_type(8))) short short8;
typedef __attribute__((ext_vector_type(16))) float f32x16;
typedef __attribute__((ext_vector_type(4))) unsigned int uint4v;

__device__ inline uint32_t f2bf(float f) {
    union { float f; uint32_t u; } x; x.f = f;
    return (x.u + 0x7FFF + ((x.u >> 16) & 1)) >> 16;
}
__device__ inline uint32_t fbits(float f) {
    union { float f; uint32_t u; } x; x.f = f;
    return x.u;
}
__device__ inline float bflo(uint32_t u) {
    union { uint32_t u; float f; } x; x.u = u << 16; return x.f;
}
__device__ inline float bfhi(uint32_t u) {
    union { uint32_t u; float f; } x; x.u = u & 0xFFFF0000u; return x.f;
}

// async 16B/lane global->LDS DMA: lds dest = uniform base + lane*16.
__device__ inline void dma16(const void* g, void* lds) {
    __builtin_amdgcn_global_load_lds(
        (const __attribute__((address_space(1))) unsigned int*)g,
        (__attribute__((address_space(3))) unsigned int*)lds, 16, 0, 0);
}

// Pass 1: X (bf16, MFMA-fragment order) + prep (bias-out init, AF build).
// X piece: tid = ((img*1024 + site)*4 + kidx)*64 + l
// AF: AF[((tap*4+kidx)*2+c)*64 + l] = 8 bf16 A-elems (verified layout, RNE).
__global__ __launch_bounds__(256) void k_xform(
    const float* __restrict__ wu, const float* __restrict__ wl,
    uint4v* __restrict__ X,
    const float* __restrict__ kk, uint4v* __restrict__ AF,
    const float* __restrict__ buI, const float* __restrict__ blI,
    float* __restrict__ buO, float* __restrict__ blO)
{
    int tid = blockIdx.x * 256 + threadIdx.x;   // 16384 blocks -> 4Mi pieces

    if (tid < 512 + 4608) {                     // folded prep
        if (tid < 256) buO[tid] = buI[tid];
        else if (tid < 512) blO[tid - 256] = blI[tid - 256];
        else {
            int a    = tid - 512;               // 4608 AF pieces
            int al   = a & 63;
            int c    = (a >> 6) & 1;
            int kidx = (a >> 7) & 3;
            int tap  = a >> 9;                  // 0..8
            const float* kp = kk + ((size_t)tap * 64 + c * 32 + (al & 31)) * 64
                                 + kidx * 16 + (al >> 5) * 8;
            uint4v w;
            #pragma unroll
            for (int pr = 0; pr < 4; pr++)
                w[pr] = f2bf(kp[2 * pr]) | (f2bf(kp[2 * pr + 1]) << 16);   // RNE
            AF[((tap * 4 + kidx) * 2 + c) * 64 + al] = w;
        }
    }

    int l    = tid & 63;
    int kidx = (tid >> 6) & 3;
    int site = (tid >> 8) & 1023;
    int img  = tid >> 18;                       // b*2 + UL
    int b    = img >> 1;
    const float* src = (img & 1) ? wl : wu;
    int o = l & 31, ch = l >> 5;

    const float* p = src + ((size_t)b * 65536 + (size_t)site * 64
                            + kidx * 16 + ch * 8) * 32 + o;
    uint4v w;
    #pragma unroll
    for (int pr = 0; pr < 4; pr++) {
        float g0 = p[(2 * pr) * 32];
        float g1 = p[(2 * pr + 1) * 32];
        w[pr] = __builtin_amdgcn_perm(fbits(g1), fbits(g0), 0x07060302u);
    }
    X[tid] = w;
}

// Pass 2: DMA-staged SINGLE-buffer LDS + max TLP (m114 mechanism).
// tiles[6][4][512] = 24576 B; VGPR ~84 -> launch_bounds(256,4): 4 blocks/CU
// = 16 waves/CU (2x R20). Per row: bar; STAGE(DMA); bar; setprio(1) COMPUTE.
// Cross-block wave overlap hides the DMA drain (no explicit dbuf needed).
__global__ __launch_bounds__(256, 4) void k_conv(
    const uint16_t* __restrict__ X, const uint16_t* __restrict__ AF,
    const float* __restrict__ bias,
    float* __restrict__ outU, float* __restrict__ outL,
    float* __restrict__ buO, float* __restrict__ blO)
{
    __shared__ uint16_t tiles[6][4][512];    // 24576 B

    int tdx  = threadIdx.x;
    int l    = tdx & 63;
    int wid  = tdx >> 6;        // 0..3
    int o    = l & 31;
    int ch   = l >> 5;
    int c    = wid >> 1;        // ci-half owned by this wave
    int wsel = wid & 1;

    int bid = blockIdx.x;       // 2048
    int b   = bid & 7;          // XCD id
    int v   = bid >> 3;         // 0..255
    int h   = v & 31;
    int wq  = v >> 5;           // 0..7
    int w0  = wq * 4 + wsel * 2;   // wave's first pixel w

    int rstart = (h == 31) ? 1 : 0;
    int nr     = (h == 0 || h == 31) ? 2 : 3;

    const char* XB  = (const char*)X;
    const char* AFB = (const char*)AF;

    for (int UL = 0; UL < 2; UL++) {
        int img = b * 2 + UL;
        float* dst  = UL ? outL : outU;
        float* bdst = UL ? blO : buO;

        float bp = 0.f;
        f32x16 acc[2];              // [tw]
        acc[0] = (f32x16)0.f;
        acc[1] = (f32x16)0.f;

        for (int i = 0; i < nr; i++) {
            int r  = rstart + i;
            int hh = h + 1 - r;                 // valid by construction

            __syncthreads();                    // previous row's readers done

            // ---- STAGE row r: this wave DMA-stages pieces wid*6 .. wid*6+5 ----
            #pragma unroll
            for (int p = 0; p < 6; p++) {
                int pc = wid * 6 + p;
                int s = pc >> 2, k = pc & 3;    // slot 0..5, kidx 0..3
                int ww = wq * 4 - 1 + s;        // wave-uniform
                void* ldst = (void*)&tiles[s][k][0];
                if ((unsigned)ww < 32u) {
                    const char* g = XB + ((size_t)(img * 1024 + hh * 32 + ww)) * 4096
                                       + (size_t)k * 1024 + (size_t)l * 16;
                    dma16(g, ldst);
                } else {
                    *(uint4v*)((char*)ldst + l * 16) = (uint4v)0u;
                }
            }

            __syncthreads();                    // DMA drained; row staged

            // ---- COMPUTE row r ----
            __builtin_amdgcn_s_setprio(1);
            #pragma unroll
            for (int kidx = 0; kidx < 4; kidx++) {
                short8 A[3];
                #pragma unroll
                for (int kw = 0; kw < 3; kw++)
                    A[kw] = *(const short8*)(AFB
                            + (size_t)((((r * 3 + kw) * 4 + kidx) * 2 + c) * 64 + l) * 16);

                uint4v bw[4];
                #pragma unroll
                for (int si = 0; si < 4; si++) {
                    int s = 2 * wsel + si;      // slot for this wave's site si
                    bw[si] = *(const uint4v*)((const char*)&tiles[s][kidx][0] + l * 16);
                }

                if (r == 1 && c == 0) {         // bias: own pixels (sites 1,2)
                    float4 b0 = *(const float4*)(bias + kidx * 16 + ch * 8);
                    float4 b1 = *(const float4*)(bias + kidx * 16 + ch * 8 + 4);
                    float bb[8] = {b0.x, b0.y, b0.z, b0.w, b1.x, b1.y, b1.z, b1.w};
                    #pragma unroll
                    for (int pr = 0; pr < 4; pr++) {
                        bp = fmaf(bflo(bw[1][pr]), bb[2 * pr],
                             fmaf(bfhi(bw[1][pr]), bb[2 * pr + 1], bp));
                        bp = fmaf(bflo(bw[2][pr]), bb[2 * pr],
                             fmaf(bfhi(bw[2][pr]), bb[2 * pr + 1], bp));
                    }
                }

                #pragma unroll
                for (int si = 0; si < 4; si++) {
                    short8 Bf = __builtin_bit_cast(short8, bw[si]);
                    #pragma unroll
                    for (int tw = 0; tw < 2; tw++) {
                        int kw = tw + 2 - si;   // compile-time under unroll
                        if (kw >= 0 && kw <= 2)
                            acc[tw] = __builtin_amdgcn_mfma_f32_32x32x16_bf16(
                                A[kw], Bf, acc[tw], 0, 0, 0);
                    }
                }
            }
            __builtin_amdgcn_s_setprio(0);
        }

        // bias reduction: lanes l, l^32 share o; c==0 wave only
        bp += __shfl_xor(bp, 32);
        if (l < 32 && c == 0) atomicAdd(&bdst[b * 32 + o], bp);

        // stores: col = o (coalesced), row = (reg&3)+8*(reg>>2)+4*(lane>>5)
        #pragma unroll
        for (int tw = 0; tw < 2; tw++) {
            int w = w0 + tw;
            float* base = dst + ((size_t)b * 65536 + (size_t)(h * 32 + w) * 64 + c * 32) * 32;
            #pragma unroll
            for (int reg = 0; reg < 16; reg++) {
                int row = (reg & 3) + 8 * (reg >> 2) + 4 * (l >> 5);
                base[row * 32 + o] = acc[tw][reg];
            }
        }
    }
}

extern "C" void kernel_launch(void* const* d_in, const int* in_sizes, int n_in,
                              void* d_out, int out_size, void* d_ws, size_t ws_size,
                              hipStream_t stream) {
    const float* wu   = (const float*)d_in[1];
    const float* buI  = (const float*)d_in[2];
    const float* wl   = (const float*)d_in[3];
    const float* blI  = (const float*)d_in[4];
    const float* kk   = (const float*)d_in[5];
    const float* bias = (const float*)d_in[6];

    float* out  = (float*)d_out;
    float* outU = out;
    float* buO  = out + 16777216;
    float* outL = out + 16777216 + 256;
    float* blO  = out + 2 * 16777216 + 256;

    uint4v* AF = (uint4v*)d_ws;                            // 73728 B
    const size_t XOFF = 131072;                            // 128 KiB aligned
    uint4v* X = (uint4v*)((char*)d_ws + XOFF);             // 64 MiB

    k_xform<<<16384, 256, 0, stream>>>(wu, wl, X, kk, AF, buI, blI, buO, blO);
    k_conv<<<2048, 256, 0, stream>>>((const uint16_t*)X, (const uint16_t*)AF, bias,
                                     outU, outL, buO, blO);
}

// Round 22
// 102.586 us; speedup vs baseline: 1.0563x; 1.0563x over previous
//
#include <hip/hip_runtime.h>
#include <cstdint>

typedef __attribute__((ext_vector_type(8))) short short8;
typedef __attribute__((ext_vector_type(16))) float f32x16;
typedef __attribute__((ext_vector_type(4))) unsigned int uint4v;

__device__ inline uint32_t f2bf(float f) {
    union { float f; uint32_t u; } x; x.f = f;
    return (x.u + 0x7FFF + ((x.u >> 16) & 1)) >> 16;
}
__device__ inline uint32_t fbits(float f) {
    union { float f; uint32_t u; } x; x.f = f;
    return x.u;
}
__device__ inline float bflo(uint32_t u) {
    union { uint32_t u; float f; } x; x.u = u << 16; return x.f;
}
__device__ inline float bfhi(uint32_t u) {
    union { uint32_t u; float f; } x; x.u = u & 0xFFFF0000u; return x.f;
}

// async 16B/lane global->LDS DMA: lds dest = uniform base + lane*16.
__device__ inline void dma16(const void* g, void* lds) {
    __builtin_amdgcn_global_load_lds(
        (const __attribute__((address_space(1))) unsigned int*)g,
        (__attribute__((address_space(3))) unsigned int*)lds, 16, 0, 0);
}

// Pass 1: X (bf16, MFMA-fragment order) + prep (bias-out init, AF build).
// X piece: tid = ((img*1024 + site)*4 + kidx)*64 + l
// AF: AF[((tap*4+kidx)*2+c)*64 + l] = 8 bf16 A-elems (verified layout, RNE).
__global__ __launch_bounds__(256) void k_xform(
    const float* __restrict__ wu, const float* __restrict__ wl,
    uint4v* __restrict__ X,
    const float* __restrict__ kk, uint4v* __restrict__ AF,
    const float* __restrict__ buI, const float* __restrict__ blI,
    float* __restrict__ buO, float* __restrict__ blO)
{
    int tid = blockIdx.x * 256 + threadIdx.x;   // 16384 blocks -> 4Mi pieces

    if (tid < 512 + 4608) {                     // folded prep
        if (tid < 256) buO[tid] = buI[tid];
        else if (tid < 512) blO[tid - 256] = blI[tid - 256];
        else {
            int a    = tid - 512;               // 4608 AF pieces
            int al   = a & 63;
            int c    = (a >> 6) & 1;
            int kidx = (a >> 7) & 3;
            int tap  = a >> 9;                  // 0..8
            const float* kp = kk + ((size_t)tap * 64 + c * 32 + (al & 31)) * 64
                                 + kidx * 16 + (al >> 5) * 8;
            uint4v w;
            #pragma unroll
            for (int pr = 0; pr < 4; pr++)
                w[pr] = f2bf(kp[2 * pr]) | (f2bf(kp[2 * pr + 1]) << 16);   // RNE
            AF[((tap * 4 + kidx) * 2 + c) * 64 + al] = w;
        }
    }

    int l    = tid & 63;
    int kidx = (tid >> 6) & 3;
    int site = (tid >> 8) & 1023;
    int img  = tid >> 18;                       // b*2 + UL
    int b    = img >> 1;
    const float* src = (img & 1) ? wl : wu;
    int o = l & 31, ch = l >> 5;

    const float* p = src + ((size_t)b * 65536 + (size_t)site * 64
                            + kidx * 16 + ch * 8) * 32 + o;
    uint4v w;
    #pragma unroll
    for (int pr = 0; pr < 4; pr++) {
        float g0 = p[(2 * pr) * 32];
        float g1 = p[(2 * pr + 1) * 32];
        w[pr] = __builtin_amdgcn_perm(fbits(g1), fbits(g0), 0x07060302u);
    }
    X[tid] = w;
}

// Pass 2: ROLLING 3-ROW WINDOW over an 8-high h-strip (steady-state pipeline).
// Block = (b, UL, wq, h-strip) = 512 blocks = exactly 2/CU. LDS = 3 slots x
// 24 KB = 72 KB. Per iteration: COMPUTE(h) [72 MFMA/wave from 3 slots]; bar;
// STAGE(row h+2) into retiring slot (1 row, DMA); stores overlap; bar.
__global__ __launch_bounds__(256, 2) void k_conv(
    const uint16_t* __restrict__ X, const uint16_t* __restrict__ AF,
    const float* __restrict__ bias,
    float* __restrict__ outU, float* __restrict__ outL,
    float* __restrict__ buO, float* __restrict__ blO)
{
    __shared__ uint16_t tiles[3][6][4][512];    // 73728 B

    int tdx  = threadIdx.x;
    int l    = tdx & 63;
    int wid  = tdx >> 6;        // 0..3
    int o    = l & 31;
    int ch   = l >> 5;
    int c    = wid >> 1;        // ci-half owned by this wave
    int wsel = wid & 1;

    int bid = blockIdx.x;       // 512
    int b   = bid & 7;          // XCD id
    int v   = bid >> 3;         // 0..63
    int hs  = v & 3;            // h-strip (8 rows)
    int wq  = (v >> 2) & 7;     // w-quad
    int UL  = v >> 5;           // 0/1
    int h0  = hs * 8;
    int w0  = wq * 4 + wsel * 2;   // wave's first pixel w
    int img = b * 2 + UL;

    float* dst  = UL ? outL : outU;
    float* bdst = UL ? blO : buO;

    const char* XB  = (const char*)X;
    const char* AFB = (const char*)AF;

    float bp = 0.f;

    // ---- STAGE(hh): this wave DMA-stages its 6 pieces of window row hh ----
    auto STAGE = [&](int hh) {
        int sl = (hh + 3) % 3;                  // slot = hh mod 3
        bool rowv = (unsigned)hh < 32u;
        #pragma unroll
        for (int p = 0; p < 6; p++) {
            int pc = wid * 6 + p;
            int s = pc >> 2, k = pc & 3;        // site slot 0..5, kidx 0..3
            int ww = wq * 4 - 1 + s;            // wave-uniform
            void* ldst = (void*)&tiles[sl][s][k][0];
            if (rowv && (unsigned)ww < 32u) {
                const char* g = XB + ((size_t)(img * 1024 + hh * 32 + ww)) * 4096
                                   + (size_t)k * 1024 + (size_t)l * 16;
                dma16(g, ldst);
            } else {
                *(uint4v*)((char*)ldst + l * 16) = (uint4v)0u;   // zero halo
            }
        }
    };

    // ---- prologue: fill the 3-row window ----
    STAGE(h0 - 1);
    STAGE(h0);
    STAGE(h0 + 1);
    __syncthreads();

    for (int i = 0; i < 8; i++) {
        int h = h0 + i;

        f32x16 acc[2];              // [tw]
        acc[0] = (f32x16)0.f;
        acc[1] = (f32x16)0.f;

        // ---- COMPUTE(h): 3 window rows x 4 kidx x 6 MFMA = 72 MFMA/wave ----
        #pragma unroll
        for (int wr = 0; wr < 3; wr++) {
            int hh = h - 1 + wr;                // window row
            int r  = 2 - wr;                    // adjoint kh index
            int sl = (hh + 3) % 3;
            #pragma unroll
            for (int kidx = 0; kidx < 4; kidx++) {
                short8 A[3];
                #pragma unroll
                for (int kw = 0; kw < 3; kw++)
                    A[kw] = *(const short8*)(AFB
                            + (size_t)((((r * 3 + kw) * 4 + kidx) * 2 + c) * 64 + l) * 16);

                uint4v bw[4];
                #pragma unroll
                for (int si = 0; si < 4; si++) {
                    int s = 2 * wsel + si;      // this wave's site slot
                    bw[si] = *(const uint4v*)((const char*)&tiles[sl][s][kidx][0] + l * 16);
                }

                if (r == 1 && c == 0) {         // bias: own pixels (sites 1,2)
                    float4 b0 = *(const float4*)(bias + kidx * 16 + ch * 8);
                    float4 b1 = *(const float4*)(bias + kidx * 16 + ch * 8 + 4);
                    float bb[8] = {b0.x, b0.y, b0.z, b0.w, b1.x, b1.y, b1.z, b1.w};
                    #pragma unroll
                    for (int pr = 0; pr < 4; pr++) {
                        bp = fmaf(bflo(bw[1][pr]), bb[2 * pr],
                             fmaf(bfhi(bw[1][pr]), bb[2 * pr + 1], bp));
                        bp = fmaf(bflo(bw[2][pr]), bb[2 * pr],
                             fmaf(bfhi(bw[2][pr]), bb[2 * pr + 1], bp));
                    }
                }

                #pragma unroll
                for (int si = 0; si < 4; si++) {
                    short8 Bf = __builtin_bit_cast(short8, bw[si]);
                    #pragma unroll
                    for (int tw = 0; tw < 2; tw++) {
                        int kw = tw + 2 - si;   // compile-time under unroll
                        if (kw >= 0 && kw <= 2)
                            acc[tw] = __builtin_amdgcn_mfma_f32_32x32x16_bf16(
                                A[kw], Bf, acc[tw], 0, 0, 0);
                    }
                }
            }
        }

        __syncthreads();                // all readers done with retiring slot

        if (i < 7) STAGE(h + 2);        // DMA next row into retiring slot

        // ---- stores overlap the DMA flight ----
        #pragma unroll
        for (int tw = 0; tw < 2; tw++) {
            int w = w0 + tw;
            float* base = dst + ((size_t)b * 65536 + (size_t)(h * 32 + w) * 64 + c * 32) * 32;
            #pragma unroll
            for (int reg = 0; reg < 16; reg++) {
                int row = (reg & 3) + 8 * (reg >> 2) + 4 * (l >> 5);
                base[row * 32 + o] = acc[tw][reg];
            }
        }

        __syncthreads();                // staged row visible for next iteration
    }

    // bias reduction: lanes l, l^32 share o; c==0 wave only
    bp += __shfl_xor(bp, 32);
    if (l < 32 && c == 0) atomicAdd(&bdst[b * 32 + o], bp);
}

extern "C" void kernel_launch(void* const* d_in, const int* in_sizes, int n_in,
                              void* d_out, int out_size, void* d_ws, size_t ws_size,
                              hipStream_t stream) {
    const float* wu   = (const float*)d_in[1];
    const float* buI  = (const float*)d_in[2];
    const float* wl   = (const float*)d_in[3];
    const float* blI  = (const float*)d_in[4];
    const float* kk   = (const float*)d_in[5];
    const float* bias = (const float*)d_in[6];

    float* out  = (float*)d_out;
    float* outU = out;
    float* buO  = out + 16777216;
    float* outL = out + 16777216 + 256;
    float* blO  = out + 2 * 16777216 + 256;

    uint4v* AF = (uint4v*)d_ws;                            // 73728 B
    const size_t XOFF = 131072;                            // 128 KiB aligned
    uint4v* X = (uint4v*)((char*)d_ws + XOFF);             // 64 MiB

    k_xform<<<16384, 256, 0, stream>>>(wu, wl, X, kk, AF, buI, blI, buO, blO);
    k_conv<<<512, 256, 0, stream>>>((const uint16_t*)X, (const uint16_t*)AF, bias,
                                    outU, outL, buO, blO);
}